// Round 2
// baseline (459.117 us; speedup 1.0000x reference)
//
#include <hip/hip_runtime.h>

// Problem: B=8192, T=240, C=16, DAYS=STRIDE=10 -> W=24 windows tiling T exactly.
// Row r = b*24+w reads contiguous x[r*160 .. r*160+159]. 320 output channels:
// [corr(120), cov(120), std(16), zscore(16), ret(16), decay(16), mean(16)].
#define NROWS   196608
#define OUTC    320
#define R_      16            // rows per LDS tile
#define WSTRIDE 164           // win LDS row stride (floats); 164%32=4 -> 2-way max in cov phase
#define CSTRIDE 121           // cov LDS row stride
#define MSTRIDE 17            // mean/std LDS row stride
#define EPS_F   1e-8f
#define EPS_BN  1e-5f
#define K1_BLOCKS 1536
#define K1_TILES  8           // 1536 * 8 * 16 = 196608 rows
#define NTILES_TOTAL 12288    // 196608 / 16

// pair p -> packed (i<<4)|j for triu_indices(16, k=1), row-major
__device__ const unsigned char PIJ[120] = {
    0x01,0x02,0x03,0x04,0x05,0x06,0x07,0x08,0x09,0x0A,0x0B,0x0C,0x0D,0x0E,0x0F,
    0x12,0x13,0x14,0x15,0x16,0x17,0x18,0x19,0x1A,0x1B,0x1C,0x1D,0x1E,0x1F,
    0x23,0x24,0x25,0x26,0x27,0x28,0x29,0x2A,0x2B,0x2C,0x2D,0x2E,0x2F,
    0x34,0x35,0x36,0x37,0x38,0x39,0x3A,0x3B,0x3C,0x3D,0x3E,0x3F,
    0x45,0x46,0x47,0x48,0x49,0x4A,0x4B,0x4C,0x4D,0x4E,0x4F,
    0x56,0x57,0x58,0x59,0x5A,0x5B,0x5C,0x5D,0x5E,0x5F,
    0x67,0x68,0x69,0x6A,0x6B,0x6C,0x6D,0x6E,0x6F,
    0x78,0x79,0x7A,0x7B,0x7C,0x7D,0x7E,0x7F,
    0x89,0x8A,0x8B,0x8C,0x8D,0x8E,0x8F,
    0x9A,0x9B,0x9C,0x9D,0x9E,0x9F,
    0xAB,0xAC,0xAD,0xAE,0xAF,
    0xBC,0xBD,0xBE,0xBF,
    0xCD,0xCE,0xCF,
    0xDE,0xDF,
    0xEF
};

// MODE=0: stats pass. dst = partial sums, transposed: part[v*K1_BLOCKS + b],
//         v in [0,320) = sum, v in [320,640) = sumsq.
// MODE=1: apply pass. dst = output, ab = {scale[320], shift[320]}.
template<int MODE>
__global__ __launch_bounds__(256)
void fe_kernel(const float* __restrict__ x, float* __restrict__ dst,
               const float* __restrict__ ab) {
    __shared__ __align__(16) float win[R_ * WSTRIDE];   // 10496 B
    __shared__ float mn[R_ * MSTRIDE];                  // 1088 B
    __shared__ float sd[R_ * MSTRIDE];                  // 1088 B
    __shared__ float cv[R_ * CSTRIDE];                  // 7744 B
    __shared__ float ex[2 * OUTC];                      // 2560 B (ab cache / stat acc)

    const int t = threadIdx.x;

    float sacc[20], sacc2[20];
    if (MODE == 0) {
#pragma unroll
        for (int k = 0; k < 20; ++k) { sacc[k] = 0.f; sacc2[k] = 0.f; }
    } else {
        // preload scale/shift (640 floats) into LDS
        ex[t] = ab[t];
        ex[t + 256] = ab[t + 256];
        if (t < 128) ex[t + 512] = ab[t + 512];
    }

    const int ntiles = (MODE == 0) ? K1_TILES : 1;
    for (int tt = 0; tt < ntiles; ++tt) {
        const int tile = (MODE == 0) ? (blockIdx.x * K1_TILES + tt) : blockIdx.x;
        const float4* src = reinterpret_cast<const float4*>(x) + (size_t)tile * (R_ * 40);

        __syncthreads();   // previous iteration readers done / ex visible
        // ---- stage 16 rows x 160 floats, coalesced float4 ----
#pragma unroll
        for (int k = 0; k < 3; ++k) {
            int q = t + k * 256;
            if (q < 640) {
                float4 v = src[q];
                int row = q / 40, pos = q % 40;
                reinterpret_cast<float4*>(win)[row * (WSTRIDE / 4) + pos] = v;
            }
        }
        __syncthreads();

        // ---- mean/std per (row, channel): 256 tasks ----
        {
            int c = t & 15, r = t >> 4;
            const float* wr = win + r * WSTRIDE + c;
            float s = 0.f;
#pragma unroll
            for (int d = 0; d < 10; ++d) s += wr[d * 16];
            float m = s * 0.1f;
            float v = 0.f;
#pragma unroll
            for (int d = 0; d < 10; ++d) { float dx = wr[d * 16] - m; v += dx * dx; }
            mn[r * MSTRIDE + c] = m;
            sd[r * MSTRIDE + c] = sqrtf(v * 0.1f);
        }
        __syncthreads();

        // ---- cov per (row, pair): 16*120 = 1920 tasks ----
#pragma unroll
        for (int k = 0; k < 8; ++k) {
            int task = t + k * 256;
            if (task < 1920) {
                int r = task & 15, p = task >> 4;
                int pj = PIJ[p];
                int i = pj >> 4, j = pj & 15;
                float mi = mn[r * MSTRIDE + i], mj = mn[r * MSTRIDE + j];
                const float* wr = win + r * WSTRIDE;
                float s = 0.f;
#pragma unroll
                for (int d = 0; d < 10; ++d)
                    s += (wr[d * 16 + i] - mi) * (wr[d * 16 + j] - mj);
                cv[r * CSTRIDE + p] = s * 0.1f;
            }
        }
        __syncthreads();

        // ---- outputs: 16*320 = 5120 elements, thread <-> element ----
#pragma unroll
        for (int k = 0; k < 20; ++k) {
            int flat = t + k * 256;
            int r = flat / 320, c = flat % 320;
            float v;
            if (c < 240) {
                int p = (c < 120) ? c : (c - 120);
                float cvv = cv[r * CSTRIDE + p];
                if (c < 120) {
                    int pj = PIJ[p];
                    int i = pj >> 4, j = pj & 15;
                    v = cvv / (sd[r * MSTRIDE + i] * sd[r * MSTRIDE + j] + EPS_F);
                } else {
                    v = cvv;
                }
            } else {
                int cc = c & 15;
                int cls = (c - 240) >> 4;   // 0:std 1:zscore 2:ret 3:decay 4:mean
                const float* wr = win + r * WSTRIDE + cc;
                float m = mn[r * MSTRIDE + cc], s = sd[r * MSTRIDE + cc];
                if (cls == 0)      v = s;
                else if (cls == 1) v = m / (s + EPS_F);
                else if (cls == 2) v = wr[144] / wr[0] - 1.0f;
                else if (cls == 3) {
                    float a = 0.f;
#pragma unroll
                    for (int d = 0; d < 10; ++d)
                        a += wr[d * 16] * ((float)(d + 1) * (1.0f / 55.0f));
                    v = a;
                } else v = m;
            }
            if (MODE == 1) {
                dst[(size_t)tile * (R_ * OUTC) + flat] = v * ex[c] + ex[OUTC + c];
            } else {
                sacc[k] += v;
                sacc2[k] += v * v;
            }
        }
    }

    if (MODE == 0) {
        // block-combine per-thread partials into per-channel LDS bins.
        // Within slot k, c = (t + k*256) % 320 is distinct across t -> no races.
        __syncthreads();
        ex[t] = 0.f; ex[t + 256] = 0.f;
        if (t < 128) ex[t + 512] = 0.f;
#pragma unroll
        for (int k = 0; k < 20; ++k) {
            __syncthreads();
            int c = (t + k * 256) % 320;
            ex[c]        += sacc[k];
            ex[OUTC + c] += sacc2[k];
        }
        __syncthreads();
        const int b = blockIdx.x;
        dst[(size_t)t * K1_BLOCKS + b]           = ex[t];
        dst[(size_t)(t + 256) * K1_BLOCKS + b]   = ex[t + 256];
        if (t < 128)
            dst[(size_t)(t + 512) * K1_BLOCKS + b] = ex[t + 512];
    }
}

// one block per channel; fp64 tree reduce over 1536 partials (deterministic)
__global__ __launch_bounds__(256)
void finalize_kernel(const float* __restrict__ part,
                     const float* __restrict__ gamma,
                     const float* __restrict__ beta,
                     float* __restrict__ ab) {
    __shared__ double rs[256], rs2[256];
    const int c = blockIdx.x, t = threadIdx.x;
    double s = 0.0, s2 = 0.0;
    for (int q = t; q < K1_BLOCKS; q += 256) {
        s  += (double)part[(size_t)c * K1_BLOCKS + q];
        s2 += (double)part[(size_t)(c + OUTC) * K1_BLOCKS + q];
    }
    rs[t] = s; rs2[t] = s2;
    __syncthreads();
    for (int off = 128; off; off >>= 1) {
        if (t < off) { rs[t] += rs[t + off]; rs2[t] += rs2[t + off]; }
        __syncthreads();
    }
    if (t == 0) {
        const double invN = 1.0 / (double)NROWS;
        double m = rs[0] * invN;
        double v = rs2[0] * invN - m * m;
        if (v < 0.0) v = 0.0;
        float a = gamma[c] / sqrtf((float)v + EPS_BN);
        ab[c] = a;
        ab[OUTC + c] = beta[c] - (float)m * a;
    }
}

extern "C" void kernel_launch(void* const* d_in, const int* in_sizes, int n_in,
                              void* d_out, int out_size, void* d_ws, size_t ws_size,
                              hipStream_t stream) {
    const float* x     = (const float*)d_in[0];
    const float* gamma = (const float*)d_in[1];
    const float* beta  = (const float*)d_in[2];
    float* out = (float*)d_out;

    float* part = (float*)d_ws;                              // 640*1536 floats = 3.93 MB
    float* ab   = part + (size_t)2 * OUTC * K1_BLOCKS;       // 640 floats

    fe_kernel<0><<<K1_BLOCKS, 256, 0, stream>>>(x, part, nullptr);
    finalize_kernel<<<2 * OUTC / 2, 256, 0, stream>>>(part, gamma, beta, ab); // 320 blocks
    fe_kernel<1><<<NTILES_TOTAL, 256, 0, stream>>>(x, out, ab);
}